// Round 10
// baseline (322.634 us; speedup 1.0000x reference)
//
#include <hip/hip_runtime.h>

// GNN: 2x SAGEConv(sum) + global_add_pool + Linear head.
// N=50000 nodes, E=1e6 edges, D=H=64, G=512 graphs, O=16.
//
// R1: CSR gather replaced scatter atomics (2111 -> 606 us).
// R2: sorted-segment pooling replaced atomic pooling (606 -> 395 us).
// R3: binned counting sort for CSR build (395 -> 367 us).
// R4: bf16 feature storage, fp32 accumulate (367 -> 325 us).
// R5: bucket-local degree counting (325 -> 302 us).
// R6: scan-free CSR; grid-stride GEMM regressed (net wash).
// R7: MFMA GEMM, K=128 N=64 bf16 16x16x32 (305 -> 240 us).
// R8: planar gather: FETCH 66->13MB (PROVED %8->XCD mapping works) but
//     26->64 us: 64 random 16B requests/wave vs 8 coalesced lines, 64-way
//     trip divergence, uncoalesced col. Transactions beat bytes. Reverted.
// R9: keep R4's coalesced full-row gather shape (8 lanes/node, one 128B
// line/edge, col broadcast) but confine gather to 2 XCDs via blockIdx%8<2
// (launch 4x blocks, 3/4 exit). Duplication 8x -> 2x: FETCH ~66 -> ~15MB,
// transaction load 1M lines on 64 CUs ~ 6.5us -> gather ~8-11 us each.

namespace {
constexpr int NN = 50000;
constexpr int NE = 1000000;
constexpr int NG = 512;
constexpr int NO = 16;
constexpr int KB = 98;                      // buckets: dst>>9 (512 nodes)
constexpr int BCAP = 16000;                 // slot capacity per bucket
constexpr int EPT = 8;                      // edges per thread (scatter)
constexpr int EPB = 256 * EPT;              // 2048 edges per block
constexpr int SBLK = (NE + EPB - 1) / EPB;  // 489 blocks
constexpr int SEDGE = 12288;                // staged edges in bucket_sort
constexpr int CVT_BLK = (NN * 64 / 8 + 255) / 256;  // 1563 cvt blocks
constexpr int GGRP = (NN * 8 + 255) / 256;  // 1563 working gather blocks
}

typedef __attribute__((ext_vector_type(8))) short bf16x8;
typedef __attribute__((ext_vector_type(4))) float f32x4;

__device__ __forceinline__ unsigned short f2bf(float f) {
  unsigned u = __float_as_uint(f);
  u += 0x7FFFu + ((u >> 16) & 1u);  // round-to-nearest-even
  return (unsigned short)(u >> 16);
}
__device__ __forceinline__ float bf2f(unsigned short s) {
  return __uint_as_float(((unsigned)s) << 16);
}

// ---------------- CSR build (scan-free bucketed counting sort) -------------

__global__ __launch_bounds__(256) void bucket_scatter(
    const int* __restrict__ ei, int* __restrict__ bcount,
    unsigned int* __restrict__ ebuf) {
  __shared__ int cnt[KB];
  __shared__ int base[KB];
  int t = threadIdx.x;
  if (t < KB) cnt[t] = 0;
  __syncthreads();
  int e0 = blockIdx.x * EPB;
  unsigned int pk[EPT];
#pragma unroll
  for (int i = 0; i < EPT; ++i) {
    int e = e0 + i * 256 + t;
    if (e < NE) {
      unsigned int src = (unsigned int)ei[e];
      unsigned int dst = (unsigned int)ei[NE + e];
      pk[i] = (dst << 16) | src;
      atomicAdd(&cnt[dst >> 9], 1);
    } else {
      pk[i] = 0xFFFFFFFFu;
    }
  }
  __syncthreads();
  if (t < KB) {
    base[t] = t * BCAP + atomicAdd(&bcount[t], cnt[t]);
    cnt[t] = 0;
  }
  __syncthreads();
#pragma unroll
  for (int i = 0; i < EPT; ++i) {
    if (pk[i] != 0xFFFFFFFFu) {
      int b = pk[i] >> 25;  // dst >> 9
      int r = atomicAdd(&cnt[b], 1);
      ebuf[base[b] + r] = pk[i];
    }
  }
}

__global__ __launch_bounds__(512) void bucket_sort(
    const unsigned int* __restrict__ ebuf, const int* __restrict__ bcount,
    unsigned int* __restrict__ meta, unsigned short* __restrict__ col) {
  __shared__ unsigned int se[SEDGE];  // 48 KB edge stage
  __shared__ int cnt[512];
  __shared__ int cur[512];
  int b = blockIdx.x;
  int t = threadIdx.x;
  int n = bcount[b];
  const unsigned int* eb = ebuf + (size_t)b * BCAP;
  cnt[t] = 0;
  __syncthreads();
  for (int j = t; j < n; j += 512) {
    unsigned int p = eb[j];
    if (j < SEDGE) se[j] = p;
    atomicAdd(&cnt[(p >> 16) & 511], 1);
  }
  __syncthreads();
  int deg = cnt[t];
  for (int off = 1; off < 512; off <<= 1) {
    int u = (t >= off) ? cnt[t - off] : 0;
    __syncthreads();
    cnt[t] += u;
    __syncthreads();
  }
  int excl = cnt[t] - deg;
  cur[t] = excl;
  int node = (b << 9) + t;
  if (node < NN) {
    meta[node] = ((unsigned)(b * BCAP + excl) << 11) | (unsigned)deg;
  }
  __syncthreads();
  unsigned short* cb = col + (size_t)b * BCAP;
  for (int j = t; j < n; j += 512) {
    unsigned int p = (j < SEDGE) ? se[j] : eb[j];
    int d = (p >> 16) & 511;
    int pos = atomicAdd(&cur[d], 1);
    cb[pos] = (unsigned short)(p & 0xFFFFu);
  }
}

// ------------- x -> row-major bf16 + transposed bf16 weights ---------------
// Blocks [0,CVT_BLK): bf16 conversion. Blocks >= CVT_BLK (64 of them):
// Wt[n][kk] = (kk<64 ? Wl[kk][n] : Wr[kk-64][n]) bf16, both layers.
__global__ __launch_bounds__(256) void cvt_prep(
    const float* __restrict__ x, unsigned short* __restrict__ x_bf,
    const float* __restrict__ Wl1, const float* __restrict__ Wr1,
    const float* __restrict__ Wl2, const float* __restrict__ Wr2,
    unsigned short* __restrict__ Wt1, unsigned short* __restrict__ Wt2) {
  int b = blockIdx.x;
  int t = threadIdx.x;
  if (b >= CVT_BLK) {
    int id = (b - CVT_BLK) * 256 + t;  // 16384 total
    int half = id >> 13;
    int e = id & 8191;
    int nrow = e >> 7;
    int kk = e & 127;
    const float* Wl = half ? Wl2 : Wl1;
    const float* Wr = half ? Wr2 : Wr1;
    unsigned short* Wt = half ? Wt2 : Wt1;
    float v = (kk < 64) ? Wl[kk * 64 + nrow] : Wr[(kk - 64) * 64 + nrow];
    Wt[nrow * 128 + kk] = f2bf(v);
    return;
  }
  int i = b * 256 + t;  // uint4 index: 8 bf16 out per thread
  if (i >= NN * 8) return;
  const float4* p = reinterpret_cast<const float4*>(x) + (size_t)i * 2;
  float4 a = p[0], bb = p[1];
  uint4 u;
  u.x = (unsigned)f2bf(a.x) | ((unsigned)f2bf(a.y) << 16);
  u.y = (unsigned)f2bf(a.z) | ((unsigned)f2bf(a.w) << 16);
  u.z = (unsigned)f2bf(bb.x) | ((unsigned)f2bf(bb.y) << 16);
  u.w = (unsigned)f2bf(bb.z) | ((unsigned)f2bf(bb.w) << 16);
  reinterpret_cast<uint4*>(x_bf)[i] = u;
}

// ---------------- aggregation (gather, 2-XCD confined) ----------------
// R4 shape: 8 lanes/node, one 16B uint4 per lane per neighbor (the 8 lanes
// cover one full 128B row-line; col[j] broadcasts across the 8 lanes).
// XCD confinement: only blockIdx%8<2 work (round-robin block->XCD mapping,
// verified by R8's FETCH drop) -> feature matrix pulled into 2 L2s, not 8.
__global__ __launch_bounds__(256) void gather_xcd(
    const unsigned short* __restrict__ feat,
    const unsigned int* __restrict__ meta,
    const unsigned short* __restrict__ col,
    unsigned short* __restrict__ agg) {
  int r = blockIdx.x & 7;
  if (r >= 2) return;  // other 6 XCDs: exit immediately
  int w = (blockIdx.x >> 3) * 2 + r;
  int gid = w * 256 + threadIdx.x;
  int v = gid >> 3;
  int q = gid & 7;
  if (v >= NN) return;
  unsigned int m = meta[v];
  int beg = (int)(m >> 11);
  int end = beg + (int)(m & 2047u);
  float acc[8] = {0.f, 0.f, 0.f, 0.f, 0.f, 0.f, 0.f, 0.f};
  const uint4* fb = reinterpret_cast<const uint4*>(feat);
  for (int j = beg; j < end; ++j) {
    int s = col[j];
    uint4 u = fb[(size_t)s * 8 + q];
    acc[0] += __uint_as_float(u.x << 16);
    acc[1] += __uint_as_float(u.x & 0xFFFF0000u);
    acc[2] += __uint_as_float(u.y << 16);
    acc[3] += __uint_as_float(u.y & 0xFFFF0000u);
    acc[4] += __uint_as_float(u.z << 16);
    acc[5] += __uint_as_float(u.z & 0xFFFF0000u);
    acc[6] += __uint_as_float(u.w << 16);
    acc[7] += __uint_as_float(u.w & 0xFFFF0000u);
  }
  uint4 o;
  o.x = (unsigned)f2bf(acc[0]) | ((unsigned)f2bf(acc[1]) << 16);
  o.y = (unsigned)f2bf(acc[2]) | ((unsigned)f2bf(acc[3]) << 16);
  o.z = (unsigned)f2bf(acc[4]) | ((unsigned)f2bf(acc[5]) << 16);
  o.w = (unsigned)f2bf(acc[6]) | ((unsigned)f2bf(acc[7]) << 16);
  reinterpret_cast<uint4*>(agg)[(size_t)v * 8 + q] = o;
}

// ---------------- MFMA GEMM (bf16 in/out, fp32 acc) ----------------
// out[row,:] = relu([A_row | H_row] @ Wt^T + b), K=128, N=64.
// One wave = 16 rows x 64 cols = 16x v_mfma_f32_16x16x32_bf16.
// Fragment maps (verified, learn_hip m89/m120):
//   A: lane m=lane&15, k=quad*8+j; B: n=lane&15, k=quad*8+j (from Wt[n][k])
//   C: col=lane&15, row=quad*4+reg
// No LDS: Wt is 16 KB, L1-resident. Layer 2 runs in-place (out==A): rows
// partitioned per wave; A loads register-consumed by MFMAs before stores.
// A/Hr/out deliberately NOT __restrict__.
__global__ __launch_bounds__(256) void sage_mfma(
    const unsigned short* A, const unsigned short* Hr,
    const unsigned short* __restrict__ Wt, const float* __restrict__ bias,
    unsigned short* out) {
  int tid = threadIdx.x;
  int wave = tid >> 6;
  int lane = tid & 63;
  int n = lane & 15;
  int q = lane >> 4;
  long base = ((long)blockIdx.x * 4 + wave) * 16;
  if (base >= NN) return;
  long rowA = base + n;
  if (rowA >= NN) rowA = NN - 1;  // clamped dup read; store predicated

  f32x4 acc[4];
#pragma unroll
  for (int t = 0; t < 4; ++t) {
    float bv = bias[t * 16 + n];
    acc[t][0] = bv;
    acc[t][1] = bv;
    acc[t][2] = bv;
    acc[t][3] = bv;
  }

  const unsigned short* arow = A + rowA * 64;
  const unsigned short* hrow = Hr + rowA * 64;
  bf16x8 af[4];
  af[0] = *(const bf16x8*)(arow + q * 8);       // k 0..31
  af[1] = *(const bf16x8*)(arow + 32 + q * 8);  // k 32..63
  af[2] = *(const bf16x8*)(hrow + q * 8);       // k 64..95
  af[3] = *(const bf16x8*)(hrow + 32 + q * 8);  // k 96..127

#pragma unroll
  for (int t = 0; t < 4; ++t) {
    const unsigned short* wrow = Wt + (size_t)(t * 16 + n) * 128 + q * 8;
#pragma unroll
    for (int s = 0; s < 4; ++s) {
      bf16x8 bfm = *(const bf16x8*)(wrow + s * 32);
      acc[t] =
          __builtin_amdgcn_mfma_f32_16x16x32_bf16(af[s], bfm, acc[t], 0, 0, 0);
    }
  }

#pragma unroll
  for (int r = 0; r < 4; ++r) {
    long rowc = base + q * 4 + r;
    if (rowc < NN) {
      unsigned short* orow = out + rowc * 64;
#pragma unroll
      for (int t = 0; t < 4; ++t) {
        orow[t * 16 + n] = f2bf(fmaxf(acc[t][r], 0.f));
      }
    }
  }
}

// ---------- pooling (sorted-segment reduction, inline search) + head -------

__global__ __launch_bounds__(64) void pool_head_kernel(
    const unsigned short* __restrict__ h2, const int* __restrict__ batch,
    const float* __restrict__ Wo, const float* __restrict__ bo,
    float* __restrict__ out) {
  __shared__ float sm[64];
  __shared__ int bounds[2];
  int g = blockIdx.x;
  int c = threadIdx.x;
  if (c < 2) {
    int target = g + c;
    int lo = 0, hi = NN;
    while (lo < hi) {
      int mid = (lo + hi) >> 1;
      if (batch[mid] < target)
        lo = mid + 1;
      else
        hi = mid;
    }
    bounds[c] = lo;
  }
  __syncthreads();
  int beg = bounds[0], end = bounds[1];
  float acc = 0.f;
  for (int i = beg; i < end; ++i) acc += bf2f(h2[(size_t)i * 64 + c]);
  sm[c] = acc;
  __syncthreads();
  if (c < NO) {
    float o = bo[c];
#pragma unroll
    for (int k = 0; k < 64; ++k) o += sm[k] * Wo[k * 16 + c];
    out[g * 16 + c] = o;
  }
}

extern "C" void kernel_launch(void* const* d_in, const int* in_sizes, int n_in,
                              void* d_out, int out_size, void* d_ws,
                              size_t ws_size, hipStream_t stream) {
  const float* x = (const float*)d_in[0];
  const int* ei = (const int*)d_in[1];
  const int* batch = (const int*)d_in[2];
  const float* Wl1 = (const float*)d_in[3];
  const float* Wr1 = (const float*)d_in[4];
  const float* b1 = (const float*)d_in[5];
  const float* Wl2 = (const float*)d_in[6];
  const float* Wr2 = (const float*)d_in[7];
  const float* b2 = (const float*)d_in[8];
  const float* Wo = (const float*)d_in[9];
  const float* bo = (const float*)d_in[10];
  float* out = (float*)d_out;

  // Workspace: 16B-aligned big arrays first, then ints.
  unsigned short* x_bf = (unsigned short*)d_ws;      // NN*64 bf16 (6.4 MB)
  unsigned short* agg_bf = x_bf + (size_t)NN * 64;   // NN*64 bf16 (6.4 MB)
  unsigned short* h1_bf = agg_bf + (size_t)NN * 64;  // NN*64 bf16 (6.4 MB)
  unsigned short* col = h1_bf + (size_t)NN * 64;     // KB*BCAP ushort (3.1MB)
  unsigned short* Wt1 = col + (size_t)KB * BCAP;     // 64*128 bf16
  unsigned short* Wt2 = Wt1 + 64 * 128;              // 64*128 bf16
  unsigned int* meta = (unsigned int*)(Wt2 + 64 * 128);  // NN
  int* bcount = (int*)(meta + NN);                   // KB
  // ebuf (KB*BCAP uint32 = 6.27MB) aliases agg_bf: consumed by bucket_sort
  // before gather first writes agg_bf.
  unsigned int* ebuf = (unsigned int*)agg_bf;

  hipMemsetAsync(bcount, 0, KB * sizeof(int), stream);

  // 4x blocks; only blockIdx%8<2 work (2-XCD confinement).
  const int gather_blocks = ((GGRP + 1) / 2) * 8;  // 6256
  const int gemm_blocks = (NN + 63) / 64;          // 782: 4 waves x 16 rows

  // x -> bf16 + transposed bf16 weights (one launch)
  cvt_prep<<<CVT_BLK + 64, 256, 0, stream>>>(x, x_bf, Wl1, Wr1, Wl2, Wr2, Wt1,
                                             Wt2);

  // CSR build (scan-free, 2 kernels)
  bucket_scatter<<<SBLK, 256, 0, stream>>>(ei, bcount, ebuf);
  bucket_sort<<<KB, 512, 0, stream>>>(ebuf, bcount, meta, col);

  // Layer 1
  gather_xcd<<<gather_blocks, 256, 0, stream>>>(x_bf, meta, col, agg_bf);
  sage_mfma<<<gemm_blocks, 256, 0, stream>>>(agg_bf, x_bf, Wt1, b1, h1_bf);

  // Layer 2 (h2 written in-place into agg_bf)
  gather_xcd<<<gather_blocks, 256, 0, stream>>>(h1_bf, meta, col, agg_bf);
  sage_mfma<<<gemm_blocks, 256, 0, stream>>>(agg_bf, h1_bf, Wt2, b2, agg_bf);

  // Pool (segmented, inline boundary search) + head
  pool_head_kernel<<<NG, 64, 0, stream>>>(agg_bf, batch, Wo, bo, out);
}

// Round 11
// 196.577 us; speedup vs baseline: 1.6413x; 1.6413x over previous
//
#include <hip/hip_runtime.h>

// GNN: 2x SAGEConv(sum) + global_add_pool + Linear head.
// N=50000 nodes, E=1e6 edges, D=H=64, G=512 graphs, O=16.
//
// R1: CSR gather replaced scatter atomics (2111 -> 606 us).
// R2: sorted-segment pooling replaced atomic pooling (606 -> 395 us).
// R3: binned counting sort for CSR build (395 -> 367 us).
// R4: bf16 feature storage, fp32 accumulate (367 -> 325 us).
// R5: bucket-local degree counting (325 -> 302 us).
// R6: scan-free CSR; grid-stride GEMM regressed (net wash).
// R7: MFMA GEMM, K=128 N=64 bf16 16x16x32 (305 -> 240 us).
// R8: planar gather: bytes 66->13MB but 64 random 16B req/wave -> 64 us. Rev.
// R9: 2-XCD-confined gather: bytes 29MB but only 64 CUs issuing -> 73 us.
//     CONCLUSION: full-machine 8x-dup gather (26 us) sits at the better of
//     the byte ceiling (LLC ~2.5TB/s) and request ceiling. It's the floor.
// R10: revert gather to R7. Fix the two remaining measurable wastes:
//  (a) bucket_scatter scattered 4B global stores (R3-style write
//      amplification) -> LDS presort per block, coalesced run copy-out.
//  (b) pooling fused into GEMM-2 epilogue (h2 never materialized; LDS
//      tile + segment walk + ~235K spread fp32 atomics) + tiny head.

namespace {
constexpr int NN = 50000;
constexpr int NE = 1000000;
constexpr int NG = 512;
constexpr int NO = 16;
constexpr int KB = 98;                      // buckets: dst>>9 (512 nodes)
constexpr int BCAP = 16000;                 // slot capacity per bucket
constexpr int EPT = 8;                      // edges per thread (scatter)
constexpr int EPB = 256 * EPT;              // 2048 edges per block
constexpr int SBLK = (NE + EPB - 1) / EPB;  // 489 blocks
constexpr int SEDGE = 12288;                // staged edges in bucket_sort
constexpr int CVT_BLK = (NN * 64 / 8 + 255) / 256;  // 1563 cvt blocks
}

typedef __attribute__((ext_vector_type(8))) short bf16x8;
typedef __attribute__((ext_vector_type(4))) float f32x4;

__device__ __forceinline__ unsigned short f2bf(float f) {
  unsigned u = __float_as_uint(f);
  u += 0x7FFFu + ((u >> 16) & 1u);  // round-to-nearest-even
  return (unsigned short)(u >> 16);
}
__device__ __forceinline__ float bf2f(unsigned short s) {
  return __uint_as_float(((unsigned)s) << 16);
}

// ---------------- CSR build (scan-free bucketed counting sort) -------------

// Pass 1 with LDS presort: block loads 2048 edges, LDS bucket histogram,
// LDS scan, LDS placement, then copies bucket-contiguous runs (~21 edges)
// to ebuf -> coalesced global writes instead of scattered 4B stores.
__global__ __launch_bounds__(256) void bucket_scatter(
    const int* __restrict__ ei, int* __restrict__ bcount,
    unsigned int* __restrict__ ebuf) {
  __shared__ unsigned int stage[EPB];  // 8 KB
  __shared__ int cnt[128];             // padded 98 -> 128
  __shared__ int lbase[128];
  __shared__ int cur[128];
  __shared__ int gbase[128];
  __shared__ int total_sh;
  int t = threadIdx.x;
  if (t < 128) cnt[t] = 0;
  __syncthreads();
  int e0 = blockIdx.x * EPB;
  unsigned int pk[EPT];
#pragma unroll
  for (int i = 0; i < EPT; ++i) {
    int e = e0 + i * 256 + t;
    if (e < NE) {
      unsigned int src = (unsigned int)ei[e];
      unsigned int dst = (unsigned int)ei[NE + e];
      pk[i] = (dst << 16) | src;
      atomicAdd(&cnt[dst >> 9], 1);
    } else {
      pk[i] = 0xFFFFFFFFu;
    }
  }
  __syncthreads();
  int deg = (t < 128) ? cnt[t] : 0;
  // Hillis-Steele inclusive scan over 128 (threads 0..127)
  for (int off = 1; off < 128; off <<= 1) {
    int u = (t >= off && t < 128) ? cnt[t - off] : 0;
    __syncthreads();
    if (t < 128) cnt[t] += u;
    __syncthreads();
  }
  if (t < 128) {
    int excl = cnt[t] - deg;
    lbase[t] = excl;
    cur[t] = excl;
    if (t < KB) gbase[t] = t * BCAP + atomicAdd(&bcount[t], deg);
    if (t == 127) total_sh = cnt[127];
  }
  __syncthreads();
#pragma unroll
  for (int i = 0; i < EPT; ++i) {
    if (pk[i] != 0xFFFFFFFFu) {
      int b = pk[i] >> 25;  // dst >> 9
      int s = atomicAdd(&cur[b], 1);
      stage[s] = pk[i];
    }
  }
  __syncthreads();
  int total = total_sh;
  for (int s = t; s < total; s += 256) {
    unsigned int p = stage[s];
    int b = p >> 25;
    ebuf[gbase[b] + (s - lbase[b])] = p;
  }
}

// One 512-thread block per bucket: stage edges in LDS, LDS degree
// histogram, LDS scan, LDS-cursor placement into col (ushort, bucket
// window), emit meta[node] = (col_beg << 11) | deg.
__global__ __launch_bounds__(512) void bucket_sort(
    const unsigned int* __restrict__ ebuf, const int* __restrict__ bcount,
    unsigned int* __restrict__ meta, unsigned short* __restrict__ col) {
  __shared__ unsigned int se[SEDGE];  // 48 KB edge stage
  __shared__ int cnt[512];
  __shared__ int cur[512];
  int b = blockIdx.x;
  int t = threadIdx.x;
  int n = bcount[b];
  const unsigned int* eb = ebuf + (size_t)b * BCAP;
  cnt[t] = 0;
  __syncthreads();
  for (int j = t; j < n; j += 512) {
    unsigned int p = eb[j];
    if (j < SEDGE) se[j] = p;
    atomicAdd(&cnt[(p >> 16) & 511], 1);
  }
  __syncthreads();
  int deg = cnt[t];
  for (int off = 1; off < 512; off <<= 1) {
    int u = (t >= off) ? cnt[t - off] : 0;
    __syncthreads();
    cnt[t] += u;
    __syncthreads();
  }
  int excl = cnt[t] - deg;
  cur[t] = excl;
  int node = (b << 9) + t;
  if (node < NN) {
    meta[node] = ((unsigned)(b * BCAP + excl) << 11) | (unsigned)deg;
  }
  __syncthreads();
  unsigned short* cb = col + (size_t)b * BCAP;
  for (int j = t; j < n; j += 512) {
    unsigned int p = (j < SEDGE) ? se[j] : eb[j];
    int d = (p >> 16) & 511;
    int pos = atomicAdd(&cur[d], 1);
    cb[pos] = (unsigned short)(p & 0xFFFFu);
  }
}

// ------------- x -> row-major bf16 + transposed bf16 weights ---------------
__global__ __launch_bounds__(256) void cvt_prep(
    const float* __restrict__ x, unsigned short* __restrict__ x_bf,
    const float* __restrict__ Wl1, const float* __restrict__ Wr1,
    const float* __restrict__ Wl2, const float* __restrict__ Wr2,
    unsigned short* __restrict__ Wt1, unsigned short* __restrict__ Wt2) {
  int b = blockIdx.x;
  int t = threadIdx.x;
  if (b >= CVT_BLK) {
    int id = (b - CVT_BLK) * 256 + t;  // 16384 total
    int half = id >> 13;
    int e = id & 8191;
    int nrow = e >> 7;
    int kk = e & 127;
    const float* Wl = half ? Wl2 : Wl1;
    const float* Wr = half ? Wr2 : Wr1;
    unsigned short* Wt = half ? Wt2 : Wt1;
    float v = (kk < 64) ? Wl[kk * 64 + nrow] : Wr[(kk - 64) * 64 + nrow];
    Wt[nrow * 128 + kk] = f2bf(v);
    return;
  }
  int i = b * 256 + t;  // uint4 index: 8 bf16 out per thread
  if (i >= NN * 8) return;
  const float4* p = reinterpret_cast<const float4*>(x) + (size_t)i * 2;
  float4 a = p[0], bb = p[1];
  uint4 u;
  u.x = (unsigned)f2bf(a.x) | ((unsigned)f2bf(a.y) << 16);
  u.y = (unsigned)f2bf(a.z) | ((unsigned)f2bf(a.w) << 16);
  u.z = (unsigned)f2bf(bb.x) | ((unsigned)f2bf(bb.y) << 16);
  u.w = (unsigned)f2bf(bb.z) | ((unsigned)f2bf(bb.w) << 16);
  reinterpret_cast<uint4*>(x_bf)[i] = u;
}

// ---------------- aggregation (gather, R7 shape — the floor) ---------------
// 8 lanes/node, one 16B uint4 per lane per neighbor (one 128B line/edge,
// col broadcast across the 8 lanes). Full machine, 8x L2 dup accepted.
__global__ __launch_bounds__(256) void gather_csr_bf(
    const unsigned short* __restrict__ feat,
    const unsigned int* __restrict__ meta,
    const unsigned short* __restrict__ col,
    unsigned short* __restrict__ agg) {
  int gid = blockIdx.x * 256 + threadIdx.x;
  int v = gid >> 3;
  int q = gid & 7;
  if (v >= NN) return;
  unsigned int m = meta[v];
  int beg = (int)(m >> 11);
  int end = beg + (int)(m & 2047u);
  float acc[8] = {0.f, 0.f, 0.f, 0.f, 0.f, 0.f, 0.f, 0.f};
  const uint4* fb = reinterpret_cast<const uint4*>(feat);
  for (int j = beg; j < end; ++j) {
    int s = col[j];
    uint4 u = fb[(size_t)s * 8 + q];
    acc[0] += __uint_as_float(u.x << 16);
    acc[1] += __uint_as_float(u.x & 0xFFFF0000u);
    acc[2] += __uint_as_float(u.y << 16);
    acc[3] += __uint_as_float(u.y & 0xFFFF0000u);
    acc[4] += __uint_as_float(u.z << 16);
    acc[5] += __uint_as_float(u.z & 0xFFFF0000u);
    acc[6] += __uint_as_float(u.w << 16);
    acc[7] += __uint_as_float(u.w & 0xFFFF0000u);
  }
  uint4 o;
  o.x = (unsigned)f2bf(acc[0]) | ((unsigned)f2bf(acc[1]) << 16);
  o.y = (unsigned)f2bf(acc[2]) | ((unsigned)f2bf(acc[3]) << 16);
  o.z = (unsigned)f2bf(acc[4]) | ((unsigned)f2bf(acc[5]) << 16);
  o.w = (unsigned)f2bf(acc[6]) | ((unsigned)f2bf(acc[7]) << 16);
  reinterpret_cast<uint4*>(agg)[(size_t)v * 8 + q] = o;
}

// ---------------- MFMA GEMM (bf16 in, fp32 acc) ----------------
// out[row,:] = relu([A_row | H_row] @ Wt^T + b), K=128, N=64.
// POOL=false: write bf16 rows to out (layer 1 -> h1).
// POOL=true: no out write; stage relu tile in LDS, walk sorted batch
// segments, atomicAdd per (graph,col) partial into pooled (layer 2).
// Fragment maps verified (learn_hip m89/m120). Wt (16KB) L1-resident.
template <bool POOL>
__global__ __launch_bounds__(256) void sage_mfma(
    const unsigned short* A, const unsigned short* Hr,
    const unsigned short* __restrict__ Wt, const float* __restrict__ bias,
    unsigned short* out, const int* __restrict__ batch,
    float* __restrict__ pooled) {
  __shared__ float psm[4][16][64];  // 16 KB (POOL only; harmless otherwise)
  int tid = threadIdx.x;
  int wave = tid >> 6;
  int lane = tid & 63;
  int n = lane & 15;
  int q = lane >> 4;
  long base = ((long)blockIdx.x * 4 + wave) * 16;
  bool active = (base < NN);
  if (!POOL && !active) return;

  if (active) {
    long rowA = base + n;
    if (rowA >= NN) rowA = NN - 1;  // clamped dup read; store predicated

    f32x4 acc[4];
#pragma unroll
    for (int t = 0; t < 4; ++t) {
      float bv = bias[t * 16 + n];
      acc[t][0] = bv;
      acc[t][1] = bv;
      acc[t][2] = bv;
      acc[t][3] = bv;
    }

    const unsigned short* arow = A + rowA * 64;
    const unsigned short* hrow = Hr + rowA * 64;
    bf16x8 af[4];
    af[0] = *(const bf16x8*)(arow + q * 8);       // k 0..31
    af[1] = *(const bf16x8*)(arow + 32 + q * 8);  // k 32..63
    af[2] = *(const bf16x8*)(hrow + q * 8);       // k 64..95
    af[3] = *(const bf16x8*)(hrow + 32 + q * 8);  // k 96..127

#pragma unroll
    for (int t = 0; t < 4; ++t) {
      const unsigned short* wrow = Wt + (size_t)(t * 16 + n) * 128 + q * 8;
#pragma unroll
      for (int s = 0; s < 4; ++s) {
        bf16x8 bfm = *(const bf16x8*)(wrow + s * 32);
        acc[t] = __builtin_amdgcn_mfma_f32_16x16x32_bf16(af[s], bfm, acc[t], 0,
                                                         0, 0);
      }
    }

    if (POOL) {
#pragma unroll
      for (int r = 0; r < 4; ++r) {
#pragma unroll
        for (int t = 0; t < 4; ++t) {
          psm[wave][q * 4 + r][t * 16 + n] = fmaxf(acc[t][r], 0.f);
        }
      }
    } else {
#pragma unroll
      for (int r = 0; r < 4; ++r) {
        long rowc = base + q * 4 + r;
        if (rowc < NN) {
          unsigned short* orow = out + rowc * 64;
#pragma unroll
          for (int t = 0; t < 4; ++t) {
            orow[t * 16 + n] = f2bf(fmaxf(acc[t][r], 0.f));
          }
        }
      }
    }
  }

  if (POOL) {
    __syncthreads();
    int c = tid & 63;
    int w = tid >> 6;
    long tbase = ((long)blockIdx.x * 4 + w) * 16;
    if (tbase < NN) {
      float run = 0.f;
      int g = batch[tbase];
      for (int i = 0; i < 16; ++i) {
        long rowi = tbase + i;
        if (rowi >= NN) break;
        int gi = batch[rowi];
        if (gi != g) {
          atomicAdd(&pooled[(size_t)g * 64 + c], run);
          run = 0.f;
          g = gi;
        }
        run += psm[w][i][c];
      }
      atomicAdd(&pooled[(size_t)g * 64 + c], run);
    }
  }
}

// ---------------- head: out[g,o] = bo[o] + pooled[g,:] @ Wo[:,o] -----------
__global__ __launch_bounds__(256) void head_kernel(
    const float* __restrict__ pooled, const float* __restrict__ Wo,
    const float* __restrict__ bo, float* __restrict__ out) {
  int id = blockIdx.x * 256 + threadIdx.x;
  if (id >= NG * NO) return;
  int g = id >> 4, o = id & 15;
  float acc = bo[o];
  const float* p = pooled + (size_t)g * 64;
#pragma unroll
  for (int k = 0; k < 64; ++k) acc += p[k] * Wo[k * 16 + o];
  out[id] = acc;
}

extern "C" void kernel_launch(void* const* d_in, const int* in_sizes, int n_in,
                              void* d_out, int out_size, void* d_ws,
                              size_t ws_size, hipStream_t stream) {
  const float* x = (const float*)d_in[0];
  const int* ei = (const int*)d_in[1];
  const int* batch = (const int*)d_in[2];
  const float* Wl1 = (const float*)d_in[3];
  const float* Wr1 = (const float*)d_in[4];
  const float* b1 = (const float*)d_in[5];
  const float* Wl2 = (const float*)d_in[6];
  const float* Wr2 = (const float*)d_in[7];
  const float* b2 = (const float*)d_in[8];
  const float* Wo = (const float*)d_in[9];
  const float* bo = (const float*)d_in[10];
  float* out = (float*)d_out;

  // Workspace: 16B-aligned big arrays first, then ints, then pooled.
  unsigned short* x_bf = (unsigned short*)d_ws;      // NN*64 bf16 (6.4 MB)
  unsigned short* agg_bf = x_bf + (size_t)NN * 64;   // NN*64 bf16 (6.4 MB)
  unsigned short* h1_bf = agg_bf + (size_t)NN * 64;  // NN*64 bf16 (6.4 MB)
  unsigned short* col = h1_bf + (size_t)NN * 64;     // KB*BCAP ushort (3.1MB)
  unsigned short* Wt1 = col + (size_t)KB * BCAP;     // 64*128 bf16
  unsigned short* Wt2 = Wt1 + 64 * 128;              // 64*128 bf16
  unsigned int* meta = (unsigned int*)(Wt2 + 64 * 128);  // NN
  int* bcount = (int*)(meta + NN);                   // KB
  float* pooled = (float*)(bcount + KB);             // NG*64 (contig w/bcount)
  // ebuf (KB*BCAP uint32 = 6.27MB) aliases agg_bf: consumed by bucket_sort
  // before gather first writes agg_bf.
  unsigned int* ebuf = (unsigned int*)agg_bf;

  // one memset covers bcount + pooled (contiguous)
  hipMemsetAsync(bcount, 0, KB * sizeof(int) + (size_t)NG * 64 * sizeof(float),
                 stream);

  const int gather_blocks = (NN * 8 + 255) / 256;  // 1563
  const int gemm_blocks = (NN + 63) / 64;          // 782: 4 waves x 16 rows

  // x -> bf16 + transposed bf16 weights (one launch)
  cvt_prep<<<CVT_BLK + 64, 256, 0, stream>>>(x, x_bf, Wl1, Wr1, Wl2, Wr2, Wt1,
                                             Wt2);

  // CSR build (scan-free, 2 kernels)
  bucket_scatter<<<SBLK, 256, 0, stream>>>(ei, bcount, ebuf);
  bucket_sort<<<KB, 512, 0, stream>>>(ebuf, bcount, meta, col);

  // Layer 1
  gather_csr_bf<<<gather_blocks, 256, 0, stream>>>(x_bf, meta, col, agg_bf);
  sage_mfma<false><<<gemm_blocks, 256, 0, stream>>>(agg_bf, x_bf, Wt1, b1,
                                                    h1_bf, batch, pooled);

  // Layer 2: gather h1 -> agg; GEMM with fused pooling (h2 never stored)
  gather_csr_bf<<<gather_blocks, 256, 0, stream>>>(h1_bf, meta, col, agg_bf);
  sage_mfma<true><<<gemm_blocks, 256, 0, stream>>>(agg_bf, h1_bf, Wt2, b2,
                                                   nullptr, batch, pooled);

  // Head from pooled (128 KB)
  head_kernel<<<(NG * NO + 255) / 256, 256, 0, stream>>>(pooled, Wo, bo, out);
}

// Round 12
// 192.721 us; speedup vs baseline: 1.6741x; 1.0200x over previous
//
#include <hip/hip_runtime.h>

// GNN: 2x SAGEConv(sum) + global_add_pool + Linear head.
// N=50000 nodes, E=1e6 edges, D=H=64, G=512 graphs, O=16.
//
// R1: CSR gather replaced scatter atomics (2111 -> 606 us).
// R2: sorted-segment pooling replaced atomic pooling (606 -> 395 us).
// R3: binned counting sort for CSR build (395 -> 367 us).
// R4: bf16 feature storage, fp32 accumulate (367 -> 325 us).
// R5: bucket-local degree counting (325 -> 302 us).
// R6: scan-free CSR; grid-stride GEMM regressed (net wash).
// R7: MFMA GEMM, K=128 N=64 bf16 16x16x32 (305 -> 240 us).
// R8/R9: gather XCD experiments — 8x-dup full-machine gather is the floor
//        (better of LLC byte ceiling and per-CU request ceiling).
// R10: LDS-presort scatter + pooling fused into GEMM-2 (240 -> 197 us).
// R11: gather fused INTO the MFMA GEMM. Lane q*16+m gathers row base+m,
// shorts {q*8..+8, 32+q*8..+8} — exactly its A-fragment — so agg never
// exists (no 6.25MB write+read per layer, no separate gather launch).
// Root-term frags af[2..3] load from the same feature buffer. Layer 2
// keeps in-LDS pooling (h2 never materialized). cvt + weight prep +
// bucket_scatter merged into one role-split launch. 6 dispatches total.

namespace {
constexpr int NN = 50000;
constexpr int NE = 1000000;
constexpr int NG = 512;
constexpr int NO = 16;
constexpr int KB = 98;                      // buckets: dst>>9 (512 nodes)
constexpr int BCAP = 16000;                 // slot capacity per bucket
constexpr int EPT = 8;                      // edges per thread (scatter)
constexpr int EPB = 256 * EPT;              // 2048 edges per block
constexpr int SBLK = (NE + EPB - 1) / EPB;  // 489 scatter blocks
constexpr int SEDGE = 12288;                // staged edges in bucket_sort
constexpr int CVT_BLK = (NN * 64 / 8 + 255) / 256;  // 1563 cvt blocks
constexpr int WP_BLK = 64;                  // weight-prep blocks
}

typedef __attribute__((ext_vector_type(8))) short bf16x8;
typedef __attribute__((ext_vector_type(4))) float f32x4;

__device__ __forceinline__ unsigned short f2bf(float f) {
  unsigned u = __float_as_uint(f);
  u += 0x7FFFu + ((u >> 16) & 1u);  // round-to-nearest-even
  return (unsigned short)(u >> 16);
}

// ---------- prep: x->bf16 | weight transpose | bucket scatter (one launch) --
// Roles by blockIdx: [0,CVT_BLK) cvt; [CVT_BLK,CVT_BLK+64) weights;
// rest: LDS-presorted bucket scatter (R10) into fixed-capacity ebuf slots.
__global__ __launch_bounds__(256) void prep_all(
    const float* __restrict__ x, unsigned short* __restrict__ x_bf,
    const float* __restrict__ Wl1, const float* __restrict__ Wr1,
    const float* __restrict__ Wl2, const float* __restrict__ Wr2,
    unsigned short* __restrict__ Wt1, unsigned short* __restrict__ Wt2,
    const int* __restrict__ ei, int* __restrict__ bcount,
    unsigned int* __restrict__ ebuf) {
  __shared__ unsigned int stage[EPB];  // 8 KB (scatter role)
  __shared__ int cnt[128];
  __shared__ int lbase[128];
  __shared__ int cur[128];
  __shared__ int gbase[128];
  __shared__ int total_sh;
  int b = blockIdx.x;
  int t = threadIdx.x;

  if (b < CVT_BLK) {  // ---- x -> bf16
    int i = b * 256 + t;
    if (i >= NN * 8) return;
    const float4* p = reinterpret_cast<const float4*>(x) + (size_t)i * 2;
    float4 a = p[0], bb = p[1];
    uint4 u;
    u.x = (unsigned)f2bf(a.x) | ((unsigned)f2bf(a.y) << 16);
    u.y = (unsigned)f2bf(a.z) | ((unsigned)f2bf(a.w) << 16);
    u.z = (unsigned)f2bf(bb.x) | ((unsigned)f2bf(bb.y) << 16);
    u.w = (unsigned)f2bf(bb.z) | ((unsigned)f2bf(bb.w) << 16);
    reinterpret_cast<uint4*>(x_bf)[i] = u;
    return;
  }
  if (b < CVT_BLK + WP_BLK) {  // ---- Wt[n][kk] transpose, both layers
    int id = (b - CVT_BLK) * 256 + t;  // 16384 total
    int half = id >> 13;
    int e = id & 8191;
    int nrow = e >> 7;
    int kk = e & 127;
    const float* Wl = half ? Wl2 : Wl1;
    const float* Wr = half ? Wr2 : Wr1;
    unsigned short* Wt = half ? Wt2 : Wt1;
    float v = (kk < 64) ? Wl[kk * 64 + nrow] : Wr[(kk - 64) * 64 + nrow];
    Wt[nrow * 128 + kk] = f2bf(v);
    return;
  }
  // ---- bucket scatter (LDS presort, coalesced run copy-out)
  int sb = b - (CVT_BLK + WP_BLK);
  if (t < 128) cnt[t] = 0;
  __syncthreads();
  int e0 = sb * EPB;
  unsigned int pk[EPT];
#pragma unroll
  for (int i = 0; i < EPT; ++i) {
    int e = e0 + i * 256 + t;
    if (e < NE) {
      unsigned int src = (unsigned int)ei[e];
      unsigned int dst = (unsigned int)ei[NE + e];
      pk[i] = (dst << 16) | src;
      atomicAdd(&cnt[dst >> 9], 1);
    } else {
      pk[i] = 0xFFFFFFFFu;
    }
  }
  __syncthreads();
  int deg = (t < 128) ? cnt[t] : 0;
  for (int off = 1; off < 128; off <<= 1) {
    int u = (t >= off && t < 128) ? cnt[t - off] : 0;
    __syncthreads();
    if (t < 128) cnt[t] += u;
    __syncthreads();
  }
  if (t < 128) {
    int excl = cnt[t] - deg;
    lbase[t] = excl;
    cur[t] = excl;
    if (t < KB) gbase[t] = t * BCAP + atomicAdd(&bcount[t], deg);
    if (t == 127) total_sh = cnt[127];
  }
  __syncthreads();
#pragma unroll
  for (int i = 0; i < EPT; ++i) {
    if (pk[i] != 0xFFFFFFFFu) {
      int bb2 = pk[i] >> 25;  // dst >> 9
      int s = atomicAdd(&cur[bb2], 1);
      stage[s] = pk[i];
    }
  }
  __syncthreads();
  int total = total_sh;
  for (int s = t; s < total; s += 256) {
    unsigned int p = stage[s];
    int bb2 = p >> 25;
    ebuf[gbase[bb2] + (s - lbase[bb2])] = p;
  }
}

// One 512-thread block per bucket: LDS hist + scan + place into col
// (ushort, bucket window), emit meta[node] = (col_beg << 11) | deg.
__global__ __launch_bounds__(512) void bucket_sort(
    const unsigned int* __restrict__ ebuf, const int* __restrict__ bcount,
    unsigned int* __restrict__ meta, unsigned short* __restrict__ col) {
  __shared__ unsigned int se[SEDGE];  // 48 KB edge stage
  __shared__ int cnt[512];
  __shared__ int cur[512];
  int b = blockIdx.x;
  int t = threadIdx.x;
  int n = bcount[b];
  const unsigned int* eb = ebuf + (size_t)b * BCAP;
  cnt[t] = 0;
  __syncthreads();
  for (int j = t; j < n; j += 512) {
    unsigned int p = eb[j];
    if (j < SEDGE) se[j] = p;
    atomicAdd(&cnt[(p >> 16) & 511], 1);
  }
  __syncthreads();
  int deg = cnt[t];
  for (int off = 1; off < 512; off <<= 1) {
    int u = (t >= off) ? cnt[t - off] : 0;
    __syncthreads();
    cnt[t] += u;
    __syncthreads();
  }
  int excl = cnt[t] - deg;
  cur[t] = excl;
  int node = (b << 9) + t;
  if (node < NN) {
    meta[node] = ((unsigned)(b * BCAP + excl) << 11) | (unsigned)deg;
  }
  __syncthreads();
  unsigned short* cb = col + (size_t)b * BCAP;
  for (int j = t; j < n; j += 512) {
    unsigned int p = (j < SEDGE) ? se[j] : eb[j];
    int d = (p >> 16) & 511;
    int pos = atomicAdd(&cur[d], 1);
    cb[pos] = (unsigned short)(p & 0xFFFFu);
  }
}

// ------------- fused gather + MFMA GEMM (+ optional pooling) ---------------
// out[row,:] = relu( (sum_{s in N(row)} feat[s]) @ Wl + feat[row] @ Wr + b )
// Wave = rows base..base+15. Lane (q=lane>>4, m=lane&15) gathers row base+m
// shorts {q*8..+8} and {32+q*8..+8} in fp32 — exactly its A-fragment for
// af[0..1] (K 0..63). af[2..3] (K 64..127, root term) load from feat[row].
// Per edge: two 16B loads hitting the same 128B row-line (2nd is L1-hit);
// col reads are quad-shared and spatially local (consecutive nodes ->
// adjacent bucket-window ranges). Fragment maps verified (m89/m120).
// POOL=true: no out write; relu tile staged in LDS, sorted-batch segment
// walk, spread fp32 atomics into pooled (R10 scheme).
template <bool POOL>
__global__ __launch_bounds__(256) void sage_fused(
    const unsigned short* __restrict__ feat,
    const unsigned int* __restrict__ meta,
    const unsigned short* __restrict__ col,
    const unsigned short* __restrict__ Wt, const float* __restrict__ bias,
    unsigned short* __restrict__ out, const int* __restrict__ batch,
    float* __restrict__ pooled) {
  __shared__ float psm[4][16][64];  // 16 KB (POOL only)
  int tid = threadIdx.x;
  int wave = tid >> 6;
  int lane = tid & 63;
  int m = lane & 15;
  int q = lane >> 4;
  long base = ((long)blockIdx.x * 4 + wave) * 16;
  bool active = (base < NN);
  if (!POOL && !active) return;

  if (active) {
    long row = base + m;
    if (row >= NN) row = NN - 1;  // clamped dup work; store predicated

    // ---- gather phase: fp32 accumulate this lane's two 8-short chunks
    unsigned int md = meta[row];
    int beg = (int)(md >> 11);
    int deg = (int)(md & 2047u);
    float ga[8] = {0.f, 0.f, 0.f, 0.f, 0.f, 0.f, 0.f, 0.f};
    float gb[8] = {0.f, 0.f, 0.f, 0.f, 0.f, 0.f, 0.f, 0.f};
    const uint4* fb = reinterpret_cast<const uint4*>(feat);
    for (int j = 0; j < deg; ++j) {
      int s = col[beg + j];
      uint4 u0 = fb[(size_t)s * 8 + q];      // row s, bytes q*16..+16
      uint4 u1 = fb[(size_t)s * 8 + 4 + q];  // row s, bytes 64+q*16..+16
      ga[0] += __uint_as_float(u0.x << 16);
      ga[1] += __uint_as_float(u0.x & 0xFFFF0000u);
      ga[2] += __uint_as_float(u0.y << 16);
      ga[3] += __uint_as_float(u0.y & 0xFFFF0000u);
      ga[4] += __uint_as_float(u0.z << 16);
      ga[5] += __uint_as_float(u0.z & 0xFFFF0000u);
      ga[6] += __uint_as_float(u0.w << 16);
      ga[7] += __uint_as_float(u0.w & 0xFFFF0000u);
      gb[0] += __uint_as_float(u1.x << 16);
      gb[1] += __uint_as_float(u1.x & 0xFFFF0000u);
      gb[2] += __uint_as_float(u1.y << 16);
      gb[3] += __uint_as_float(u1.y & 0xFFFF0000u);
      gb[4] += __uint_as_float(u1.z << 16);
      gb[5] += __uint_as_float(u1.z & 0xFFFF0000u);
      gb[6] += __uint_as_float(u1.w << 16);
      gb[7] += __uint_as_float(u1.w & 0xFFFF0000u);
    }
    bf16x8 af[4];
#pragma unroll
    for (int i = 0; i < 8; ++i) {
      af[0][i] = (short)f2bf(ga[i]);
      af[1][i] = (short)f2bf(gb[i]);
    }
    // root-term fragments from feat[row]
    const unsigned short* hrow = feat + row * 64;
    af[2] = *(const bf16x8*)(hrow + q * 8);       // k 64..95
    af[3] = *(const bf16x8*)(hrow + 32 + q * 8);  // k 96..127

    // ---- MFMA phase
    f32x4 acc[4];
#pragma unroll
    for (int t = 0; t < 4; ++t) {
      float bv = bias[t * 16 + m];
      acc[t][0] = bv;
      acc[t][1] = bv;
      acc[t][2] = bv;
      acc[t][3] = bv;
    }
#pragma unroll
    for (int t = 0; t < 4; ++t) {
      const unsigned short* wrow = Wt + (size_t)(t * 16 + m) * 128 + q * 8;
#pragma unroll
      for (int s = 0; s < 4; ++s) {
        bf16x8 bfm = *(const bf16x8*)(wrow + s * 32);
        acc[t] = __builtin_amdgcn_mfma_f32_16x16x32_bf16(af[s], bfm, acc[t], 0,
                                                         0, 0);
      }
    }

    // ---- epilogue
    if (POOL) {
#pragma unroll
      for (int r = 0; r < 4; ++r) {
#pragma unroll
        for (int t = 0; t < 4; ++t) {
          psm[wave][q * 4 + r][t * 16 + m] = fmaxf(acc[t][r], 0.f);
        }
      }
    } else {
#pragma unroll
      for (int r = 0; r < 4; ++r) {
        long rowc = base + q * 4 + r;
        if (rowc < NN) {
          unsigned short* orow = out + rowc * 64;
#pragma unroll
          for (int t = 0; t < 4; ++t) {
            orow[t * 16 + m] = f2bf(fmaxf(acc[t][r], 0.f));
          }
        }
      }
    }
  }

  if (POOL) {
    __syncthreads();
    int c = tid & 63;
    int w = tid >> 6;
    long tbase = ((long)blockIdx.x * 4 + w) * 16;
    if (tbase < NN) {
      float run = 0.f;
      int g = batch[tbase];
      for (int i = 0; i < 16; ++i) {
        long rowi = tbase + i;
        if (rowi >= NN) break;
        int gi = batch[rowi];
        if (gi != g) {
          atomicAdd(&pooled[(size_t)g * 64 + c], run);
          run = 0.f;
          g = gi;
        }
        run += psm[w][i][c];
      }
      atomicAdd(&pooled[(size_t)g * 64 + c], run);
    }
  }
}

// ---------------- head: out[g,o] = bo[o] + pooled[g,:] @ Wo[:,o] -----------
__global__ __launch_bounds__(256) void head_kernel(
    const float* __restrict__ pooled, const float* __restrict__ Wo,
    const float* __restrict__ bo, float* __restrict__ out) {
  int id = blockIdx.x * 256 + threadIdx.x;
  if (id >= NG * NO) return;
  int g = id >> 4, o = id & 15;
  float acc = bo[o];
  const float* p = pooled + (size_t)g * 64;
#pragma unroll
  for (int k = 0; k < 64; ++k) acc += p[k] * Wo[k * 16 + o];
  out[id] = acc;
}

extern "C" void kernel_launch(void* const* d_in, const int* in_sizes, int n_in,
                              void* d_out, int out_size, void* d_ws,
                              size_t ws_size, hipStream_t stream) {
  const float* x = (const float*)d_in[0];
  const int* ei = (const int*)d_in[1];
  const int* batch = (const int*)d_in[2];
  const float* Wl1 = (const float*)d_in[3];
  const float* Wr1 = (const float*)d_in[4];
  const float* b1 = (const float*)d_in[5];
  const float* Wl2 = (const float*)d_in[6];
  const float* Wr2 = (const float*)d_in[7];
  const float* b2 = (const float*)d_in[8];
  const float* Wo = (const float*)d_in[9];
  const float* bo = (const float*)d_in[10];
  float* out = (float*)d_out;

  // Workspace (no aliasing needed anymore; ~22.7 MB of 256+ MB):
  unsigned short* x_bf = (unsigned short*)d_ws;     // NN*64 bf16 (6.4 MB)
  unsigned short* h1_bf = x_bf + (size_t)NN * 64;   // NN*64 bf16 (6.4 MB)
  unsigned short* col = h1_bf + (size_t)NN * 64;    // KB*BCAP ushort (3.1MB)
  unsigned short* Wt1 = col + (size_t)KB * BCAP;    // 64*128 bf16
  unsigned short* Wt2 = Wt1 + 64 * 128;             // 64*128 bf16
  unsigned int* ebuf = (unsigned int*)(Wt2 + 64 * 128);  // KB*BCAP (6.27MB)
  unsigned int* meta = ebuf + (size_t)KB * BCAP;    // NN
  int* bcount = (int*)(meta + NN);                  // KB
  float* pooled = (float*)(bcount + KB);            // NG*64 (contig w/bcount)

  // one memset covers bcount + pooled (contiguous)
  hipMemsetAsync(bcount, 0, KB * sizeof(int) + (size_t)NG * 64 * sizeof(float),
                 stream);

  const int gemm_blocks = (NN + 63) / 64;  // 782: 4 waves x 16 rows

  // prep: x->bf16 | weight transpose | bucket scatter (one role-split launch)
  prep_all<<<CVT_BLK + WP_BLK + SBLK, 256, 0, stream>>>(
      x, x_bf, Wl1, Wr1, Wl2, Wr2, Wt1, Wt2, ei, bcount, ebuf);

  // CSR finalize
  bucket_sort<<<KB, 512, 0, stream>>>(ebuf, bcount, meta, col);

  // Layer 1: fused gather+GEMM, writes h1
  sage_fused<false><<<gemm_blocks, 256, 0, stream>>>(
      x_bf, meta, col, Wt1, b1, h1_bf, batch, pooled);

  // Layer 2: fused gather+GEMM+pool (h2 never materialized)
  sage_fused<true><<<gemm_blocks, 256, 0, stream>>>(
      h1_bf, meta, col, Wt2, b2, nullptr, batch, pooled);

  // Head from pooled (128 KB)
  head_kernel<<<(NG * NO + 255) / 256, 256, 0, stream>>>(pooled, Wo, bo, out);
}